// Round 12
// baseline (436.075 us; speedup 1.0000x reference)
//
#include <hip/hip_runtime.h>
#include <hip/hip_bf16.h>

#define BATCH 2
#define SEQ   2048
#define DMODEL 1024
#define NHEAD 16
#define DEPTH 64
#define NBANDS 7

// Allowed diffs: causal AND (local<=32 OR |log2(d)-round|<0.1), derived exactly:
//   [0,34] [60,68] [120,137] [239,274] [478,548] [956,1097] [1911,2047]
__device__ __constant__ int cBLO[NBANDS] = {0, 60, 120, 239, 478, 956, 1911};
__device__ __constant__ int cBHI[NBANDS] = {34, 68, 137, 274, 548, 1097, 2047};

typedef __attribute__((ext_vector_type(4))) float f32x4;
typedef __attribute__((ext_vector_type(8))) short bf16x8;
#define MFMA16(a, b, c) __builtin_amdgcn_mfma_f32_16x16x32_bf16(a, b, c, 0, 0, 0)

__device__ __forceinline__ unsigned short f2bf(float x) {
    unsigned int u = __float_as_uint(x);
    u += 0x7fffu + ((u >> 16) & 1u);   // RNE
    return (unsigned short)(u >> 16);
}

// ---------------------------------------------------------------------------
// input converts (fused): z=0 q, z=1 k, z=2 v  ->  plain bf16 [4096][1024]
// ---------------------------------------------------------------------------
__global__ __launch_bounds__(256) void cvt_inputs(
    const float* __restrict__ q, const float* __restrict__ k, const float* __restrict__ v,
    unsigned short* __restrict__ qb16, unsigned short* __restrict__ kb16,
    unsigned short* __restrict__ vb16)
{
    const int z = blockIdx.y;
    const float* x = (z == 0) ? q : (z == 1) ? k : v;
    unsigned short* o = (z == 0) ? qb16 : (z == 1) ? kb16 : vb16;
    size_t f = ((size_t)blockIdx.x * 256 + threadIdx.x) * 8;
    float4 v0 = *(const float4*)(x + f);
    float4 v1 = *(const float4*)(x + f + 4);
    float val[8] = {v0.x, v0.y, v0.z, v0.w, v1.x, v1.y, v1.z, v1.w};
    unsigned short hi[8];
    #pragma unroll
    for (int j = 0; j < 8; ++j) hi[j] = f2bf(val[j]);
    *(uint4*)(o + f) = *(uint4*)hi;
}

// ---------------------------------------------------------------------------
// weight transpose+convert (fused): z = 0..3 -> WT bf16 [1024][1024] (n-major)
// ---------------------------------------------------------------------------
__global__ __launch_bounds__(256) void cvt_w(
    const float* __restrict__ Wq, const float* __restrict__ Wk,
    const float* __restrict__ Wv, const float* __restrict__ Wo,
    unsigned short* __restrict__ WqT, unsigned short* __restrict__ WkT,
    unsigned short* __restrict__ WvT, unsigned short* __restrict__ WoT)
{
    const int z = blockIdx.z;
    const float* W = (z == 0) ? Wq : (z == 1) ? Wk : (z == 2) ? Wv : Wo;
    unsigned short* WT = (z == 0) ? WqT : (z == 1) ? WkT : (z == 2) ? WvT : WoT;

    const int k0 = blockIdx.x * 64, n0 = blockIdx.y * 64;
    __shared__ float T[64][65];
    const int t = threadIdx.x;
    const int r = t >> 2, cc = (t & 3) * 16;
    {
        const float* src = W + (size_t)(k0 + r) * 1024 + n0 + cc;
        #pragma unroll
        for (int j = 0; j < 4; ++j) {
            float4 a = *(const float4*)(src + 4 * j);
            T[r][cc + 4 * j + 0] = a.x; T[r][cc + 4 * j + 1] = a.y;
            T[r][cc + 4 * j + 2] = a.z; T[r][cc + 4 * j + 3] = a.w;
        }
    }
    __syncthreads();
    const int d = t >> 2;
    unsigned short hi[16];
    #pragma unroll
    for (int j = 0; j < 16; ++j) hi[j] = f2bf(T[cc + j][d]);
    unsigned short* dst = WT + (size_t)(n0 + d) * 1024 + k0 + cc;
    *(uint4*)dst       = *(uint4*)hi;
    *(uint4*)(dst + 8) = *(uint4*)(hi + 8);
}

// ---------------------------------------------------------------------------
// MFMA GEMM core: 128x128 tile, BK=64, 4 waves (2x2), XOR-swizzled LDS.
// ---------------------------------------------------------------------------
__device__ __forceinline__ void gemm_core(
    const unsigned short* __restrict__ A, const unsigned short* __restrict__ BT,
    int Kc, unsigned short* Atile, unsigned short* Btile,
    f32x4 (&acc)[4][4], int rowBase, int colBase, int tid, int lane, int wm, int wn)
{
    #pragma unroll
    for (int mt = 0; mt < 4; ++mt)
        #pragma unroll
        for (int nt = 0; nt < 4; ++nt) {
            acc[mt][nt].x = 0.f; acc[mt][nt].y = 0.f;
            acc[mt][nt].z = 0.f; acc[mt][nt].w = 0.f;
        }
    const int srow = tid >> 3;
    const int sch  = tid & 7;
    uint4 ar[4], br[4];

    #define ISSUE(k0)                                                          \
        _Pragma("unroll")                                                      \
        for (int i = 0; i < 4; ++i) {                                          \
            int row = srow + i * 32;                                           \
            ar[i] = *(const uint4*)(A  + (size_t)(rowBase + row) * Kc + (k0) + sch * 8); \
            br[i] = *(const uint4*)(BT + (size_t)(colBase + row) * Kc + (k0) + sch * 8); \
        }

    ISSUE(0)
    const int nk = Kc >> 6;
    for (int t = 0; t < nk; ++t) {
        __syncthreads();
        #pragma unroll
        for (int i = 0; i < 4; ++i) {
            int row = srow + i * 32;
            int off = row * 128 + ((sch * 16) ^ ((row & 7) << 4));
            *(uint4*)((char*)Atile + off) = ar[i];
            *(uint4*)((char*)Btile + off) = br[i];
        }
        __syncthreads();
        if (t + 1 < nk) { int k0n = (t + 1) << 6; ISSUE(k0n) }

        bf16x8 a0[4], a1[4];
        const int g = (lane >> 4) * 16;
        #pragma unroll
        for (int mt = 0; mt < 4; ++mt) {
            int arow = wm + mt * 16 + (lane & 15);
            const char* base = (const char*)Atile + arow * 128;
            int sw = (arow & 7) << 4;
            a0[mt] = *(const bf16x8*)(base + (g ^ sw));
            a1[mt] = *(const bf16x8*)(base + ((g + 64) ^ sw));
        }
        #pragma unroll
        for (int nt = 0; nt < 4; ++nt) {
            int brow = wn + nt * 16 + (lane & 15);
            const char* base = (const char*)Btile + brow * 128;
            int sw = (brow & 7) << 4;
            bf16x8 b0 = *(const bf16x8*)(base + (g ^ sw));
            bf16x8 b1 = *(const bf16x8*)(base + ((g + 64) ^ sw));
            #pragma unroll
            for (int mt = 0; mt < 4; ++mt) {
                acc[mt][nt] = MFMA16(a0[mt], b0, acc[mt][nt]);
                acc[mt][nt] = MFMA16(a1[mt], b1, acc[mt][nt]);
            }
        }
    }
    #undef ISSUE
}

// fused QKV projections, all K=1024: z=0 Q(*0.125)->qbb, z=1 K->kbb,
// z=2 V->vbT[b][h][d][c] (fused transpose epilogue)
__global__ __launch_bounds__(256) void gemm_qkv(
    const unsigned short* __restrict__ qb16, const unsigned short* __restrict__ kb16,
    const unsigned short* __restrict__ vb16,
    const unsigned short* __restrict__ WqT, const unsigned short* __restrict__ WkT,
    const unsigned short* __restrict__ WvT,
    const float* __restrict__ bq, const float* __restrict__ bk,
    const float* __restrict__ bv,
    unsigned short* __restrict__ qbb, unsigned short* __restrict__ kbb,
    unsigned short* __restrict__ vbT)
{
    __shared__ unsigned short Atile[128 * 64];
    __shared__ unsigned short Btile[128 * 64];
    const int z = blockIdx.z;
    const unsigned short* A  = (z == 0) ? qb16 : (z == 1) ? kb16 : vb16;
    const unsigned short* BT = (z == 0) ? WqT  : (z == 1) ? WkT  : WvT;
    const float* bias        = (z == 0) ? bq   : (z == 1) ? bk   : bv;
    const float scale        = (z == 0) ? 0.125f : 1.0f;

    const int tid  = threadIdx.x;
    const int lane = tid & 63;
    const int wave = tid >> 6;
    const int wm = (wave >> 1) * 64;
    const int wn = (wave & 1) * 64;
    const int rowBase = blockIdx.y * 128;
    const int colBase = blockIdx.x * 128;

    f32x4 acc[4][4];
    gemm_core(A, BT, 1024, Atile, Btile, acc, rowBase, colBase, tid, lane, wm, wn);

    const int gg = lane >> 4;
    #pragma unroll
    for (int nt = 0; nt < 4; ++nt) {
        int col = colBase + wn + nt * 16 + (lane & 15);
        float bv_ = bias[col];
        if (z == 2) {
            int h = col >> 6, d = col & 63;
            #pragma unroll
            for (int mt = 0; mt < 4; ++mt) {
                int row0 = rowBase + wm + mt * 16 + gg * 4;
                int bb_ = row0 >> 11, cc = row0 & 2047;
                unsigned long long pk =
                      (unsigned long long)f2bf(acc[mt][nt][0] + bv_)
                    | ((unsigned long long)f2bf(acc[mt][nt][1] + bv_) << 16)
                    | ((unsigned long long)f2bf(acc[mt][nt][2] + bv_) << 32)
                    | ((unsigned long long)f2bf(acc[mt][nt][3] + bv_) << 48);
                *(unsigned long long*)(vbT +
                    (((size_t)((bb_ * NHEAD + h) * DEPTH + d)) << 11) + cc) = pk;
            }
        } else {
            unsigned short* C = (z == 0) ? qbb : kbb;
            #pragma unroll
            for (int mt = 0; mt < 4; ++mt) {
                #pragma unroll
                for (int r = 0; r < 4; ++r) {
                    int row = rowBase + wm + mt * 16 + gg * 4 + r;
                    C[(size_t)row * 1024 + col] = f2bf((acc[mt][nt][r] + bv_) * scale);
                }
            }
        }
    }
}

// output projection: f32 out
__global__ __launch_bounds__(256) void gemm_out(
    const unsigned short* __restrict__ A, const unsigned short* __restrict__ BT,
    const float* __restrict__ bias, float* __restrict__ C)
{
    __shared__ unsigned short Atile[128 * 64];
    __shared__ unsigned short Btile[128 * 64];
    const int tid  = threadIdx.x;
    const int lane = tid & 63;
    const int wave = tid >> 6;
    const int wm = (wave >> 1) * 64;
    const int wn = (wave & 1) * 64;
    const int rowBase = blockIdx.y * 128;
    const int colBase = blockIdx.x * 128;

    f32x4 acc[4][4];
    gemm_core(A, BT, 1024, Atile, Btile, acc, rowBase, colBase, tid, lane, wm, wn);

    const int gg = lane >> 4;
    #pragma unroll
    for (int nt = 0; nt < 4; ++nt) {
        int col = colBase + wn + nt * 16 + (lane & 15);
        float bv_ = bias[col];
        #pragma unroll
        for (int mt = 0; mt < 4; ++mt) {
            #pragma unroll
            for (int r = 0; r < 4; ++r) {
                int row = rowBase + wm + mt * 16 + gg * 4 + r;
                C[(size_t)row * 1024 + col] = acc[mt][nt][r] + bv_;
            }
        }
    }
}

// ---------------------------------------------------------------------------
// LDS-only barrier: orders LDS ops (lgkmcnt) across the block WITHOUT the
// vmcnt(0) drain __syncthreads emits — in-flight global STORES (the dense
// attn writes) ride across. Safe: each wave's own LDS reads/writes are
// complete (lgkmcnt(0)) before it arrives; barrier orders waves.
// ---------------------------------------------------------------------------
__device__ __forceinline__ void barrier_lds() {
    asm volatile("s_waitcnt lgkmcnt(0)" ::: "memory");
    __builtin_amdgcn_s_barrier();
}

// 64x64 bf16 tile staging split into load-to-regs / write-to-LDS (256 thr,
// 2 uint4 each) so next-chunk loads issue BEFORE this chunk's stores and
// the ds_write's counted vmcnt wait doesn't drain the store queue.
__device__ __forceinline__ void tile_load(
    uint4 r[2], const unsigned short* __restrict__ src, int stride, int tid)
{
    #pragma unroll
    for (int j = 0; j < 2; ++j) {
        int t = tid + j * 256;
        r[j] = *(const uint4*)(src + (size_t)(t >> 3) * stride + (t & 7) * 8);
    }
}
__device__ __forceinline__ void tile_write(
    unsigned short* dst, const uint4 r[2], int tid)
{
    #pragma unroll
    for (int j = 0; j < 2; ++j) {
        int t = tid + j * 256;
        int row = t >> 3, c8 = t & 7;
        *(uint4*)((char*)dst + row * 128 + ((c8 * 16) ^ ((row & 7) << 4))) = r[j];
    }
}

// ---------------------------------------------------------------------------
// MFMA attention: R8 two-pass structure with IDENTICAL arithmetic; only the
// chunk-loop plumbing changes: raw LDS barriers (no vmcnt drain) + register
// double-buffer prefetch of next chunk's K/V.
// ---------------------------------------------------------------------------
__global__ __launch_bounds__(256) void attn_mfma(
    const unsigned short* __restrict__ qb, const unsigned short* __restrict__ kb,
    const unsigned short* __restrict__ vbT,
    float* __restrict__ attn, unsigned short* __restrict__ ctxb)
{
    const int tid  = threadIdx.x;
    const int lane = tid & 63;
    const int wave = tid >> 6;
    const int qt = blockIdx.x, h = blockIdx.y, b = blockIdx.z;
    const int i0 = qt * 64;

    __shared__ unsigned short K_lds[64 * 64];
    __shared__ unsigned short V_lds[64 * 64];
    __shared__ unsigned short P_lds[4][16 * 64];
    __shared__ unsigned long long bmask[32];

    if (tid < 32) {
        unsigned long long w = 0;
        for (int j = 0; j < 64; ++j) {
            int d = tid * 64 + j;
            bool a = false;
            #pragma unroll
            for (int bb = 0; bb < NBANDS; ++bb)
                a = a || (d >= cBLO[bb] && d <= cBHI[bb]);
            if (a) w |= (1ull << j);
        }
        bmask[tid] = w;
    }

    unsigned int amask = 0;
    for (int ch = 0; ch < 32; ++ch) {
        int c0 = ch * 64;
        bool act = false;
        #pragma unroll
        for (int bb = 0; bb < NBANDS; ++bb)
            act = act || ((c0 <= i0 + 63 - cBLO[bb]) && (c0 + 63 >= i0 - cBHI[bb]));
        if (act) amask |= (1u << ch);
    }

    const unsigned short* kbg = kb + (size_t)b * SEQ * DMODEL + h * DEPTH;
    const unsigned short* vbg = vbT + ((size_t)((b * NHEAD + h) * DEPTH)) * SEQ;

    const int qrow = i0 + wave * 16 + (lane & 15);
    const unsigned short* qptr =
        qb + ((size_t)(b * SEQ + qrow)) * DMODEL + h * DEPTH + (lane >> 4) * 8;
    bf16x8 qa0 = *(const bf16x8*)qptr;
    bf16x8 qa1 = *(const bf16x8*)(qptr + 32);

    const int rgrp = (lane >> 4) << 2;
    const int ibase = i0 + wave * 16 + rgrp;

    // ---------------- pass 1: row sums ----------------
    float rsum[4] = {0.f, 0.f, 0.f, 0.f};
    {
        unsigned int m = amask;                     // nonzero: d=0 always allowed
        int ch = (int)__builtin_ctz(m);
        uint4 kr[2];
        tile_load(kr, kbg + (size_t)(ch * 64) * DMODEL, DMODEL, tid);
        while (true) {
            const int c0 = ch * 64;
            m &= m - 1;
            barrier_lds();                           // prev LDS reads done
            tile_write(K_lds, kr, tid);
            const int nch = m ? (int)__builtin_ctz(m) : 0;
            if (m) tile_load(kr, kbg + (size_t)(nch * 64) * DMODEL, DMODEL, tid);
            barrier_lds();                           // staging visible

            f32x4 s[4];
            #pragma unroll
            for (int nt = 0; nt < 4; ++nt) { s[nt].x = 0.f; s[nt].y = 0.f; s[nt].z = 0.f; s[nt].w = 0.f; }
            #pragma unroll
            for (int nt = 0; nt < 4; ++nt) {
                int krow = nt * 16 + (lane & 15);
                const char* kbase = (const char*)K_lds + krow * 128;
                int sw = (krow & 7) << 4;
                bf16x8 b0 = *(const bf16x8*)(kbase + ((((lane >> 4) * 16) + 0) ^ sw));
                bf16x8 b1 = *(const bf16x8*)(kbase + ((((lane >> 4) * 16) + 64) ^ sw));
                s[nt] = MFMA16(qa0, b0, s[nt]);
                s[nt] = MFMA16(qa1, b1, s[nt]);
            }
            #pragma unroll
            for (int nt = 0; nt < 4; ++nt) {
                int c = c0 + nt * 16 + (lane & 15);
                #pragma unroll
                for (int r = 0; r < 4; ++r) {
                    int d = ibase + r - c;
                    float e = 0.f;
                    if (d >= 0 && ((bmask[d >> 6] >> (d & 63)) & 1ull))
                        e = __expf(s[nt][r]);
                    rsum[r] += e;
                }
            }
            if (!m) break;
            ch = nch;
        }
    }
    #pragma unroll
    for (int r = 0; r < 4; ++r) {
        float v = rsum[r];
        v += __shfl_xor(v, 1); v += __shfl_xor(v, 2);
        v += __shfl_xor(v, 4); v += __shfl_xor(v, 8);
        rsum[r] = 1.0f / v;
    }

    // ---------------- pass 2: attn write + PV ----------------
    f32x4 o[4];
    #pragma unroll
    for (int nt = 0; nt < 4; ++nt) { o[nt].x = 0.f; o[nt].y = 0.f; o[nt].z = 0.f; o[nt].w = 0.f; }

    float* ablock = attn + ((size_t)((b * NHEAD + h) * SEQ)) * SEQ;

    {
        unsigned int m = amask;
        int ch = (int)__builtin_ctz(m);
        uint4 kr[2], vr[2];
        tile_load(kr, kbg + (size_t)(ch * 64) * DMODEL, DMODEL, tid);
        tile_load(vr, vbg + ch * 64, SEQ, tid);

        // zero chunks: fire-and-forget burst (issued AFTER prologue loads,
        // so the first tile_write's counted wait isn't blocked by them)
        for (int zc = 0; zc < 32; ++zc) {
            if ((amask >> zc) & 1u) continue;
            const int c0 = zc * 64;
            float4 z = {0.f, 0.f, 0.f, 0.f};
            #pragma unroll
            for (int rr = 0; rr < 4; ++rr) {
                int i = i0 + wave * 16 + rr * 4 + (lane >> 4);
                *(float4*)(ablock + (size_t)i * SEQ + c0 + (lane & 15) * 4) = z;
            }
        }

        while (true) {
            const int c0 = ch * 64;
            m &= m - 1;
            barrier_lds();
            tile_write(K_lds, kr, tid);
            tile_write(V_lds, vr, tid);
            const int nch = m ? (int)__builtin_ctz(m) : 0;
            if (m) {
                tile_load(kr, kbg + (size_t)(nch * 64) * DMODEL, DMODEL, tid);
                tile_load(vr, vbg + nch * 64, SEQ, tid);
            }
            barrier_lds();

            f32x4 s[4];
            #pragma unroll
            for (int nt = 0; nt < 4; ++nt) { s[nt].x = 0.f; s[nt].y = 0.f; s[nt].z = 0.f; s[nt].w = 0.f; }
            #pragma unroll
            for (int nt = 0; nt < 4; ++nt) {
                int krow = nt * 16 + (lane & 15);
                const char* kbase = (const char*)K_lds + krow * 128;
                int sw = (krow & 7) << 4;
                bf16x8 b0 = *(const bf16x8*)(kbase + ((((lane >> 4) * 16) + 0) ^ sw));
                bf16x8 b1 = *(const bf16x8*)(kbase + ((((lane >> 4) * 16) + 64) ^ sw));
                s[nt] = MFMA16(qa0, b0, s[nt]);
                s[nt] = MFMA16(qa1, b1, s[nt]);
            }

            char* pwav = (char*)&P_lds[wave][0];
            #pragma unroll
            for (int nt = 0; nt < 4; ++nt) {
                int c = c0 + nt * 16 + (lane & 15);
                #pragma unroll
                for (int r = 0; r < 4; ++r) {
                    int row_local = rgrp + r;
                    int i = i0 + wave * 16 + row_local;
                    int d = i - c;
                    float e = 0.f;
                    if (d >= 0 && ((bmask[d >> 6] >> (d & 63)) & 1ull))
                        e = __expf(s[nt][r]) * rsum[r];
                    ablock[(size_t)i * SEQ + c] = e;
                    int colb = (nt * 16 + (lane & 15)) * 2;
                    *(unsigned short*)(pwav + row_local * 128 + (colb ^ ((row_local & 7) << 4))) = f2bf(e);
                }
            }
            const char* pbase = (const char*)&P_lds[wave][0] + (lane & 15) * 128;
            int swp = ((lane & 15) & 7) << 4;
            bf16x8 pa0 = *(const bf16x8*)(pbase + ((((lane >> 4) * 16) + 0) ^ swp));
            bf16x8 pa1 = *(const bf16x8*)(pbase + ((((lane >> 4) * 16) + 64) ^ swp));
            #pragma unroll
            for (int nt = 0; nt < 4; ++nt) {
                int vrow = nt * 16 + (lane & 15);
                const char* vbase = (const char*)V_lds + vrow * 128;
                int sw = (vrow & 7) << 4;
                bf16x8 b0 = *(const bf16x8*)(vbase + ((((lane >> 4) * 16) + 0) ^ sw));
                bf16x8 b1 = *(const bf16x8*)(vbase + ((((lane >> 4) * 16) + 64) ^ sw));
                o[nt] = MFMA16(pa0, b0, o[nt]);
                o[nt] = MFMA16(pa1, b1, o[nt]);
            }
            if (!m) break;
            ch = nch;
        }
    }

    // ---------------- ctx store (bf16) ----------------
    #pragma unroll
    for (int nt = 0; nt < 4; ++nt) {
        int d = nt * 16 + (lane & 15);
        #pragma unroll
        for (int r = 0; r < 4; ++r) {
            int i = i0 + wave * 16 + rgrp + r;
            ctxb[((size_t)(b * SEQ + i)) * DMODEL + h * DEPTH + d] = f2bf(o[nt][r]);
        }
    }
}

// ---------------------------------------------------------------------------
extern "C" void kernel_launch(void* const* d_in, const int* in_sizes, int n_in,
                              void* d_out, int out_size, void* d_ws, size_t ws_size,
                              hipStream_t stream) {
    const float* v  = (const float*)d_in[0];
    const float* k  = (const float*)d_in[1];
    const float* q  = (const float*)d_in[2];
    const float* Wq = (const float*)d_in[3];
    const float* bq = (const float*)d_in[4];
    const float* Wk = (const float*)d_in[5];
    const float* bk = (const float*)d_in[6];
    const float* Wv = (const float*)d_in[7];
    const float* bv = (const float*)d_in[8];
    const float* Wo = (const float*)d_in[9];
    const float* bo = (const float*)d_in[10];

    float* out  = (float*)d_out;                   // [B*S, D]
    float* attn = out + 4194304;                   // [B, H, S, S]  (512 MB)

    // --- d_ws layout (34 MB) — everything that must survive attn_mfma ---
    unsigned short* qbb  = (unsigned short*)d_ws;            // 8 MB bf16
    unsigned short* kbb  = qbb  + 4194304;                   // 8 MB
    unsigned short* vbT  = kbb  + 4194304;                   // 8 MB
    unsigned short* ctxb = vbT  + 4194304;                   // 8 MB
    unsigned short* WoT  = ctxb + 4194304;                   // 2 MB

    // --- scratch inside attn region (dead before attn_mfma writes it) ---
    unsigned short* qb16 = (unsigned short*)attn;            // 8 MB
    unsigned short* kb16 = qb16 + 4194304;                   // 8 MB
    unsigned short* vb16 = kb16 + 4194304;                   // 8 MB
    unsigned short* WqT  = vb16 + 4194304;                   // 2 MB
    unsigned short* WkT  = WqT  + 1048576;                   // 2 MB
    unsigned short* WvT  = WkT  + 1048576;                   // 2 MB

    cvt_inputs<<<dim3(2048, 3), 256, 0, stream>>>(q, k, v, qb16, kb16, vb16);
    cvt_w<<<dim3(16, 16, 4), 256, 0, stream>>>(Wq, Wk, Wv, Wo, WqT, WkT, WvT, WoT);

    // fused QKV projections, all K=1024 (768 blocks = 3/CU)
    gemm_qkv<<<dim3(8, 32, 3), 256, 0, stream>>>(
        qb16, kb16, vb16, WqT, WkT, WvT, bq, bk, bv, qbb, kbb, vbT);

    attn_mfma<<<dim3(SEQ / 64, NHEAD, BATCH), 256, 0, stream>>>(qbb, kbb, vbT, attn, ctxb);

    gemm_out<<<dim3(8, 32), 256, 0, stream>>>(ctxb, WoT, bo, out);
}

// Round 14
// 363.209 us; speedup vs baseline: 1.2006x; 1.2006x over previous
//
#include <hip/hip_runtime.h>
#include <hip/hip_bf16.h>

#define BATCH 2
#define SEQ   2048
#define DMODEL 1024
#define NHEAD 16
#define DEPTH 64
#define NBANDS 7

// Allowed diffs: causal AND (local<=32 OR |log2(d)-round|<0.1), derived exactly:
//   [0,34] [60,68] [120,137] [239,274] [478,548] [956,1097] [1911,2047]
__device__ __constant__ int cBLO[NBANDS] = {0, 60, 120, 239, 478, 956, 1911};
__device__ __constant__ int cBHI[NBANDS] = {34, 68, 137, 274, 548, 1097, 2047};

typedef __attribute__((ext_vector_type(4))) float f32x4;
typedef __attribute__((ext_vector_type(8))) short bf16x8;
#define MFMA16(a, b, c) __builtin_amdgcn_mfma_f32_16x16x32_bf16(a, b, c, 0, 0, 0)

__device__ __forceinline__ unsigned short f2bf(float x) {
    unsigned int u = __float_as_uint(x);
    u += 0x7fffu + ((u >> 16) & 1u);   // RNE
    return (unsigned short)(u >> 16);
}

// ---------------------------------------------------------------------------
// input converts (fused): z=0 q, z=1 k, z=2 v  ->  plain bf16 [4096][1024]
// ---------------------------------------------------------------------------
__global__ __launch_bounds__(256) void cvt_inputs(
    const float* __restrict__ q, const float* __restrict__ k, const float* __restrict__ v,
    unsigned short* __restrict__ qb16, unsigned short* __restrict__ kb16,
    unsigned short* __restrict__ vb16)
{
    const int z = blockIdx.y;
    const float* x = (z == 0) ? q : (z == 1) ? k : v;
    unsigned short* o = (z == 0) ? qb16 : (z == 1) ? kb16 : vb16;
    size_t f = ((size_t)blockIdx.x * 256 + threadIdx.x) * 8;
    float4 v0 = *(const float4*)(x + f);
    float4 v1 = *(const float4*)(x + f + 4);
    float val[8] = {v0.x, v0.y, v0.z, v0.w, v1.x, v1.y, v1.z, v1.w};
    unsigned short hi[8];
    #pragma unroll
    for (int j = 0; j < 8; ++j) hi[j] = f2bf(val[j]);
    *(uint4*)(o + f) = *(uint4*)hi;
}

// ---------------------------------------------------------------------------
// weight transpose+convert (fused): z = 0..3 -> WT bf16 [1024][1024] (n-major)
// ---------------------------------------------------------------------------
__global__ __launch_bounds__(256) void cvt_w(
    const float* __restrict__ Wq, const float* __restrict__ Wk,
    const float* __restrict__ Wv, const float* __restrict__ Wo,
    unsigned short* __restrict__ WqT, unsigned short* __restrict__ WkT,
    unsigned short* __restrict__ WvT, unsigned short* __restrict__ WoT)
{
    const int z = blockIdx.z;
    const float* W = (z == 0) ? Wq : (z == 1) ? Wk : (z == 2) ? Wv : Wo;
    unsigned short* WT = (z == 0) ? WqT : (z == 1) ? WkT : (z == 2) ? WvT : WoT;

    const int k0 = blockIdx.x * 64, n0 = blockIdx.y * 64;
    __shared__ float T[64][65];
    const int t = threadIdx.x;
    const int r = t >> 2, cc = (t & 3) * 16;
    {
        const float* src = W + (size_t)(k0 + r) * 1024 + n0 + cc;
        #pragma unroll
        for (int j = 0; j < 4; ++j) {
            float4 a = *(const float4*)(src + 4 * j);
            T[r][cc + 4 * j + 0] = a.x; T[r][cc + 4 * j + 1] = a.y;
            T[r][cc + 4 * j + 2] = a.z; T[r][cc + 4 * j + 3] = a.w;
        }
    }
    __syncthreads();
    const int d = t >> 2;
    unsigned short hi[16];
    #pragma unroll
    for (int j = 0; j < 16; ++j) hi[j] = f2bf(T[cc + j][d]);
    unsigned short* dst = WT + (size_t)(n0 + d) * 1024 + k0 + cc;
    *(uint4*)dst       = *(uint4*)hi;
    *(uint4*)(dst + 8) = *(uint4*)(hi + 8);
}

// ---------------------------------------------------------------------------
// MFMA GEMM core: 128x128 tile, BK=64, 4 waves (2x2), XOR-swizzled LDS.
// ---------------------------------------------------------------------------
__device__ __forceinline__ void gemm_core(
    const unsigned short* __restrict__ A, const unsigned short* __restrict__ BT,
    int Kc, unsigned short* Atile, unsigned short* Btile,
    f32x4 (&acc)[4][4], int rowBase, int colBase, int tid, int lane, int wm, int wn)
{
    #pragma unroll
    for (int mt = 0; mt < 4; ++mt)
        #pragma unroll
        for (int nt = 0; nt < 4; ++nt) {
            acc[mt][nt].x = 0.f; acc[mt][nt].y = 0.f;
            acc[mt][nt].z = 0.f; acc[mt][nt].w = 0.f;
        }
    const int srow = tid >> 3;
    const int sch  = tid & 7;
    uint4 ar[4], br[4];

    #define ISSUE(k0)                                                          \
        _Pragma("unroll")                                                      \
        for (int i = 0; i < 4; ++i) {                                          \
            int row = srow + i * 32;                                           \
            ar[i] = *(const uint4*)(A  + (size_t)(rowBase + row) * Kc + (k0) + sch * 8); \
            br[i] = *(const uint4*)(BT + (size_t)(colBase + row) * Kc + (k0) + sch * 8); \
        }

    ISSUE(0)
    const int nk = Kc >> 6;
    for (int t = 0; t < nk; ++t) {
        __syncthreads();
        #pragma unroll
        for (int i = 0; i < 4; ++i) {
            int row = srow + i * 32;
            int off = row * 128 + ((sch * 16) ^ ((row & 7) << 4));
            *(uint4*)((char*)Atile + off) = ar[i];
            *(uint4*)((char*)Btile + off) = br[i];
        }
        __syncthreads();
        if (t + 1 < nk) { int k0n = (t + 1) << 6; ISSUE(k0n) }

        bf16x8 a0[4], a1[4];
        const int g = (lane >> 4) * 16;
        #pragma unroll
        for (int mt = 0; mt < 4; ++mt) {
            int arow = wm + mt * 16 + (lane & 15);
            const char* base = (const char*)Atile + arow * 128;
            int sw = (arow & 7) << 4;
            a0[mt] = *(const bf16x8*)(base + (g ^ sw));
            a1[mt] = *(const bf16x8*)(base + ((g + 64) ^ sw));
        }
        #pragma unroll
        for (int nt = 0; nt < 4; ++nt) {
            int brow = wn + nt * 16 + (lane & 15);
            const char* base = (const char*)Btile + brow * 128;
            int sw = (brow & 7) << 4;
            bf16x8 b0 = *(const bf16x8*)(base + (g ^ sw));
            bf16x8 b1 = *(const bf16x8*)(base + ((g + 64) ^ sw));
            #pragma unroll
            for (int mt = 0; mt < 4; ++mt) {
                acc[mt][nt] = MFMA16(a0[mt], b0, acc[mt][nt]);
                acc[mt][nt] = MFMA16(a1[mt], b1, acc[mt][nt]);
            }
        }
    }
    #undef ISSUE
}

// fused QKV projections, all K=1024: z=0 Q(*0.125)->qbb, z=1 K->kbb,
// z=2 V->vbT[b][h][d][c] (fused transpose epilogue)
__global__ __launch_bounds__(256) void gemm_qkv(
    const unsigned short* __restrict__ qb16, const unsigned short* __restrict__ kb16,
    const unsigned short* __restrict__ vb16,
    const unsigned short* __restrict__ WqT, const unsigned short* __restrict__ WkT,
    const unsigned short* __restrict__ WvT,
    const float* __restrict__ bq, const float* __restrict__ bk,
    const float* __restrict__ bv,
    unsigned short* __restrict__ qbb, unsigned short* __restrict__ kbb,
    unsigned short* __restrict__ vbT)
{
    __shared__ unsigned short Atile[128 * 64];
    __shared__ unsigned short Btile[128 * 64];
    const int z = blockIdx.z;
    const unsigned short* A  = (z == 0) ? qb16 : (z == 1) ? kb16 : vb16;
    const unsigned short* BT = (z == 0) ? WqT  : (z == 1) ? WkT  : WvT;
    const float* bias        = (z == 0) ? bq   : (z == 1) ? bk   : bv;
    const float scale        = (z == 0) ? 0.125f : 1.0f;

    const int tid  = threadIdx.x;
    const int lane = tid & 63;
    const int wave = tid >> 6;
    const int wm = (wave >> 1) * 64;
    const int wn = (wave & 1) * 64;
    const int rowBase = blockIdx.y * 128;
    const int colBase = blockIdx.x * 128;

    f32x4 acc[4][4];
    gemm_core(A, BT, 1024, Atile, Btile, acc, rowBase, colBase, tid, lane, wm, wn);

    const int gg = lane >> 4;
    #pragma unroll
    for (int nt = 0; nt < 4; ++nt) {
        int col = colBase + wn + nt * 16 + (lane & 15);
        float bv_ = bias[col];
        if (z == 2) {
            int h = col >> 6, d = col & 63;
            #pragma unroll
            for (int mt = 0; mt < 4; ++mt) {
                int row0 = rowBase + wm + mt * 16 + gg * 4;
                int bb_ = row0 >> 11, cc = row0 & 2047;
                unsigned long long pk =
                      (unsigned long long)f2bf(acc[mt][nt][0] + bv_)
                    | ((unsigned long long)f2bf(acc[mt][nt][1] + bv_) << 16)
                    | ((unsigned long long)f2bf(acc[mt][nt][2] + bv_) << 32)
                    | ((unsigned long long)f2bf(acc[mt][nt][3] + bv_) << 48);
                *(unsigned long long*)(vbT +
                    (((size_t)((bb_ * NHEAD + h) * DEPTH + d)) << 11) + cc) = pk;
            }
        } else {
            unsigned short* C = (z == 0) ? qbb : kbb;
            #pragma unroll
            for (int mt = 0; mt < 4; ++mt) {
                #pragma unroll
                for (int r = 0; r < 4; ++r) {
                    int row = rowBase + wm + mt * 16 + gg * 4 + r;
                    C[(size_t)row * 1024 + col] = f2bf((acc[mt][nt][r] + bv_) * scale);
                }
            }
        }
    }
}

// output projection: f32 out
__global__ __launch_bounds__(256) void gemm_out(
    const unsigned short* __restrict__ A, const unsigned short* __restrict__ BT,
    const float* __restrict__ bias, float* __restrict__ C)
{
    __shared__ unsigned short Atile[128 * 64];
    __shared__ unsigned short Btile[128 * 64];
    const int tid  = threadIdx.x;
    const int lane = tid & 63;
    const int wave = tid >> 6;
    const int wm = (wave >> 1) * 64;
    const int wn = (wave & 1) * 64;
    const int rowBase = blockIdx.y * 128;
    const int colBase = blockIdx.x * 128;

    f32x4 acc[4][4];
    gemm_core(A, BT, 1024, Atile, Btile, acc, rowBase, colBase, tid, lane, wm, wn);

    const int gg = lane >> 4;
    #pragma unroll
    for (int nt = 0; nt < 4; ++nt) {
        int col = colBase + wn + nt * 16 + (lane & 15);
        float bv_ = bias[col];
        #pragma unroll
        for (int mt = 0; mt < 4; ++mt) {
            #pragma unroll
            for (int r = 0; r < 4; ++r) {
                int row = rowBase + wm + mt * 16 + gg * 4 + r;
                C[(size_t)row * 1024 + col] = acc[mt][nt][r] + bv_;
            }
        }
    }
}

// ---------------------------------------------------------------------------
// stage a 64x64 bf16 tile into LDS (128B rows) with G4 XOR swizzle
// ---------------------------------------------------------------------------
__device__ __forceinline__ void stage64x64(
    unsigned short* dst, const unsigned short* __restrict__ src,
    int srcStride, int tid)
{
    #pragma unroll
    for (int t = tid; t < 512; t += 256) {
        int row = t >> 3, ch = t & 7;
        uint4 v = *(const uint4*)(src + (size_t)row * srcStride + ch * 8);
        *(uint4*)((char*)dst + row * 128 + ((ch * 16) ^ ((row & 7) << 4))) = v;
    }
}

// ---------------------------------------------------------------------------
// MFMA attention (R8 structure, arithmetic frozen). Delta vs R8:
//  (1) all attn stores are NON-TEMPORAL (write-once 512 MB stream must not
//      thrash the per-XCD 4MB L2 that K/V staging reads live in);
//  (2) zero-chunk writes hoisted before pass 1 (fire-and-forget overlap).
// NOTE: __builtin_nontemporal_store requires scalar or clang-vector types;
// use f32x4 (ext_vector_type), NOT HIP's float4 struct.
// ---------------------------------------------------------------------------
__global__ __launch_bounds__(256) void attn_mfma(
    const unsigned short* __restrict__ qb, const unsigned short* __restrict__ kb,
    const unsigned short* __restrict__ vbT,
    float* __restrict__ attn, unsigned short* __restrict__ ctxb)
{
    const int tid  = threadIdx.x;
    const int lane = tid & 63;
    const int wave = tid >> 6;
    const int qt = blockIdx.x, h = blockIdx.y, b = blockIdx.z;
    const int i0 = qt * 64;

    __shared__ unsigned short K_lds[64 * 64];
    __shared__ unsigned short V_lds[64 * 64];
    __shared__ unsigned short P_lds[4][16 * 64];
    __shared__ unsigned long long bmask[32];

    if (tid < 32) {
        unsigned long long w = 0;
        for (int j = 0; j < 64; ++j) {
            int d = tid * 64 + j;
            bool a = false;
            #pragma unroll
            for (int bb = 0; bb < NBANDS; ++bb)
                a = a || (d >= cBLO[bb] && d <= cBHI[bb]);
            if (a) w |= (1ull << j);
        }
        bmask[tid] = w;
    }

    unsigned int amask = 0;
    for (int ch = 0; ch < 32; ++ch) {
        int c0 = ch * 64;
        bool act = false;
        #pragma unroll
        for (int bb = 0; bb < NBANDS; ++bb)
            act = act || ((c0 <= i0 + 63 - cBLO[bb]) && (c0 + 63 >= i0 - cBHI[bb]));
        if (act) amask |= (1u << ch);
    }

    float* ablock = attn + ((size_t)((b * NHEAD + h) * SEQ)) * SEQ;

    // zero chunks up front: fire-and-forget non-temporal burst, overlaps pass 1
    for (int ch = 0; ch < 32; ++ch) {
        if ((amask >> ch) & 1u) continue;
        const int c0 = ch * 64;
        f32x4 z = {0.f, 0.f, 0.f, 0.f};
        #pragma unroll
        for (int rr = 0; rr < 4; ++rr) {
            int i = i0 + wave * 16 + rr * 4 + (lane >> 4);
            __builtin_nontemporal_store(z,
                (f32x4*)(ablock + (size_t)i * SEQ + c0 + (lane & 15) * 4));
        }
    }

    const int qrow = i0 + wave * 16 + (lane & 15);
    const unsigned short* qptr =
        qb + ((size_t)(b * SEQ + qrow)) * DMODEL + h * DEPTH + (lane >> 4) * 8;
    bf16x8 qa0 = *(const bf16x8*)qptr;
    bf16x8 qa1 = *(const bf16x8*)(qptr + 32);

    const int rgrp = (lane >> 4) << 2;
    const int ibase = i0 + wave * 16 + rgrp;

    // ---------------- pass 1: row sums ----------------
    float rsum[4] = {0.f, 0.f, 0.f, 0.f};
    for (int ch = 0; ch < 32; ++ch) {
        if (!((amask >> ch) & 1u)) continue;
        const int c0 = ch * 64;
        __syncthreads();
        stage64x64(K_lds, kb + ((size_t)(b * SEQ + c0)) * DMODEL + h * DEPTH, DMODEL, tid);
        __syncthreads();

        f32x4 s[4];
        #pragma unroll
        for (int nt = 0; nt < 4; ++nt) { s[nt].x = 0.f; s[nt].y = 0.f; s[nt].z = 0.f; s[nt].w = 0.f; }
        #pragma unroll
        for (int nt = 0; nt < 4; ++nt) {
            int krow = nt * 16 + (lane & 15);
            const char* kbase = (const char*)K_lds + krow * 128;
            int sw = (krow & 7) << 4;
            bf16x8 b0 = *(const bf16x8*)(kbase + ((((lane >> 4) * 16) + 0) ^ sw));
            bf16x8 b1 = *(const bf16x8*)(kbase + ((((lane >> 4) * 16) + 64) ^ sw));
            s[nt] = MFMA16(qa0, b0, s[nt]);
            s[nt] = MFMA16(qa1, b1, s[nt]);
        }
        #pragma unroll
        for (int nt = 0; nt < 4; ++nt) {
            int c = c0 + nt * 16 + (lane & 15);
            #pragma unroll
            for (int r = 0; r < 4; ++r) {
                int d = ibase + r - c;
                float e = 0.f;
                if (d >= 0 && ((bmask[d >> 6] >> (d & 63)) & 1ull))
                    e = __expf(s[nt][r]);
                rsum[r] += e;
            }
        }
    }
    #pragma unroll
    for (int r = 0; r < 4; ++r) {
        float v = rsum[r];
        v += __shfl_xor(v, 1); v += __shfl_xor(v, 2);
        v += __shfl_xor(v, 4); v += __shfl_xor(v, 8);
        rsum[r] = 1.0f / v;
    }

    // ---------------- pass 2: attn write + PV ----------------
    f32x4 o[4];
    #pragma unroll
    for (int nt = 0; nt < 4; ++nt) { o[nt].x = 0.f; o[nt].y = 0.f; o[nt].z = 0.f; o[nt].w = 0.f; }

    for (int ch = 0; ch < 32; ++ch) {
        const int c0 = ch * 64;
        if (!((amask >> ch) & 1u)) continue;   // zeros already written
        __syncthreads();
        stage64x64(K_lds, kb + ((size_t)(b * SEQ + c0)) * DMODEL + h * DEPTH, DMODEL, tid);
        stage64x64(V_lds, vbT + ((size_t)((b * NHEAD + h) * DEPTH)) * SEQ + c0, SEQ, tid);
        __syncthreads();

        f32x4 s[4];
        #pragma unroll
        for (int nt = 0; nt < 4; ++nt) { s[nt].x = 0.f; s[nt].y = 0.f; s[nt].z = 0.f; s[nt].w = 0.f; }
        #pragma unroll
        for (int nt = 0; nt < 4; ++nt) {
            int krow = nt * 16 + (lane & 15);
            const char* kbase = (const char*)K_lds + krow * 128;
            int sw = (krow & 7) << 4;
            bf16x8 b0 = *(const bf16x8*)(kbase + ((((lane >> 4) * 16) + 0) ^ sw));
            bf16x8 b1 = *(const bf16x8*)(kbase + ((((lane >> 4) * 16) + 64) ^ sw));
            s[nt] = MFMA16(qa0, b0, s[nt]);
            s[nt] = MFMA16(qa1, b1, s[nt]);
        }

        char* pwav = (char*)&P_lds[wave][0];
        #pragma unroll
        for (int nt = 0; nt < 4; ++nt) {
            int c = c0 + nt * 16 + (lane & 15);
            #pragma unroll
            for (int r = 0; r < 4; ++r) {
                int row_local = rgrp + r;
                int i = i0 + wave * 16 + row_local;
                int d = i - c;
                float e = 0.f;
                if (d >= 0 && ((bmask[d >> 6] >> (d & 63)) & 1ull))
                    e = __expf(s[nt][r]) * rsum[r];
                __builtin_nontemporal_store(e, ablock + (size_t)i * SEQ + c);
                int colb = (nt * 16 + (lane & 15)) * 2;
                *(unsigned short*)(pwav + row_local * 128 + (colb ^ ((row_local & 7) << 4))) = f2bf(e);
            }
        }
        const char* pbase = (const char*)&P_lds[wave][0] + (lane & 15) * 128;
        int swp = ((lane & 15) & 7) << 4;
        bf16x8 pa0 = *(const bf16x8*)(pbase + ((((lane >> 4) * 16) + 0) ^ swp));
        bf16x8 pa1 = *(const bf16x8*)(pbase + ((((lane >> 4) * 16) + 64) ^ swp));
        #pragma unroll
        for (int nt = 0; nt < 4; ++nt) {
            int vrow = nt * 16 + (lane & 15);
            const char* vbase = (const char*)V_lds + vrow * 128;
            int sw = (vrow & 7) << 4;
            bf16x8 b0 = *(const bf16x8*)(vbase + ((((lane >> 4) * 16) + 0) ^ sw));
            bf16x8 b1 = *(const bf16x8*)(vbase + ((((lane >> 4) * 16) + 64) ^ sw));
            o[nt] = MFMA16(pa0, b0, o[nt]);
            o[nt] = MFMA16(pa1, b1, o[nt]);
        }
    }

    // ---------------- ctx store (bf16) ----------------
    #pragma unroll
    for (int nt = 0; nt < 4; ++nt) {
        int d = nt * 16 + (lane & 15);
        #pragma unroll
        for (int r = 0; r < 4; ++r) {
            int i = i0 + wave * 16 + rgrp + r;
            ctxb[((size_t)(b * SEQ + i)) * DMODEL + h * DEPTH + d] = f2bf(o[nt][r]);
        }
    }
}

// ---------------------------------------------------------------------------
extern "C" void kernel_launch(void* const* d_in, const int* in_sizes, int n_in,
                              void* d_out, int out_size, void* d_ws, size_t ws_size,
                              hipStream_t stream) {
    const float* v  = (const float*)d_in[0];
    const float* k  = (const float*)d_in[1];
    const float* q  = (const float*)d_in[2];
    const float* Wq = (const float*)d_in[3];
    const float* bq = (const float*)d_in[4];
    const float* Wk = (const float*)d_in[5];
    const float* bk = (const float*)d_in[6];
    const float* Wv = (const float*)d_in[7];
    const float* bv = (const float*)d_in[8];
    const float* Wo = (const float*)d_in[9];
    const float* bo = (const float*)d_in[10];

    float* out  = (float*)d_out;                   // [B*S, D]
    float* attn = out + 4194304;                   // [B, H, S, S]  (512 MB)

    // --- d_ws layout (34 MB) — everything that must survive attn_mfma ---
    unsigned short* qbb  = (unsigned short*)d_ws;            // 8 MB bf16
    unsigned short* kbb  = qbb  + 4194304;                   // 8 MB
    unsigned short* vbT  = kbb  + 4194304;                   // 8 MB
    unsigned short* ctxb = vbT  + 4194304;                   // 8 MB
    unsigned short* WoT  = ctxb + 4194304;                   // 2 MB

    // --- scratch inside attn region (dead before attn_mfma writes it) ---
    unsigned short* qb16 = (unsigned short*)attn;            // 8 MB
    unsigned short* kb16 = qb16 + 4194304;                   // 8 MB
    unsigned short* vb16 = kb16 + 4194304;                   // 8 MB
    unsigned short* WqT  = vb16 + 4194304;                   // 2 MB
    unsigned short* WkT  = WqT  + 1048576;                   // 2 MB
    unsigned short* WvT  = WkT  + 1048576;                   // 2 MB

    cvt_inputs<<<dim3(2048, 3), 256, 0, stream>>>(q, k, v, qb16, kb16, vb16);
    cvt_w<<<dim3(16, 16, 4), 256, 0, stream>>>(Wq, Wk, Wv, Wo, WqT, WkT, WvT, WoT);

    // fused QKV projections, all K=1024 (768 blocks = 3/CU)
    gemm_qkv<<<dim3(8, 32, 3), 256, 0, stream>>>(
        qb16, kb16, vb16, WqT, WkT, WvT, bq, bk, bv, qbb, kbb, vbT);

    attn_mfma<<<dim3(SEQ / 64, NHEAD, BATCH), 256, 0, stream>>>(qbb, kbb, vbT, attn, ctxb);

    gemm_out<<<dim3(8, 32), 256, 0, stream>>>(ctxb, WoT, bo, out);
}

// Round 15
// 255.712 us; speedup vs baseline: 1.7053x; 1.4204x over previous
//
#include <hip/hip_runtime.h>
#include <hip/hip_bf16.h>

#define BATCH 2
#define SEQ   2048
#define DMODEL 1024
#define NHEAD 16
#define DEPTH 64
#define NBANDS 7

// Allowed diffs: causal AND (local<=32 OR |log2(d)-round|<0.1), derived exactly:
//   [0,34] [60,68] [120,137] [239,274] [478,548] [956,1097] [1911,2047]
__device__ __constant__ int cBLO[NBANDS] = {0, 60, 120, 239, 478, 956, 1911};
__device__ __constant__ int cBHI[NBANDS] = {34, 68, 137, 274, 548, 1097, 2047};

typedef __attribute__((ext_vector_type(4))) float f32x4;
typedef __attribute__((ext_vector_type(8))) short bf16x8;
#define MFMA16(a, b, c) __builtin_amdgcn_mfma_f32_16x16x32_bf16(a, b, c, 0, 0, 0)

__device__ __forceinline__ unsigned short f2bf(float x) {
    unsigned int u = __float_as_uint(x);
    u += 0x7fffu + ((u >> 16) & 1u);   // RNE
    return (unsigned short)(u >> 16);
}

// ---------------------------------------------------------------------------
// async global->LDS 16B DMA. LDS dest is LINEAR (wave-uniform base + lane*16,
// rule #21); the XOR swizzle is applied to the per-lane GLOBAL source address
// (same involution as the read side), so final LDS contents are bit-identical
// to the old reg-staged swizzled writes.
// ---------------------------------------------------------------------------
#if __has_builtin(__builtin_amdgcn_global_load_lds)
#define HAVE_GLOAD_LDS 1
__device__ __forceinline__ void gload16(const void* g, void* lds) {
    __builtin_amdgcn_global_load_lds(
        (const __attribute__((address_space(1))) unsigned int*)(unsigned long long)g,
        (__attribute__((address_space(3))) unsigned int*)(unsigned int)(unsigned long long)lds,
        16, 0, 0);
}
#else
#define HAVE_GLOAD_LDS 0
#endif

// ---------------------------------------------------------------------------
// input converts (fused): z=0 q, z=1 k, z=2 v  ->  plain bf16 [4096][1024]
// ---------------------------------------------------------------------------
__global__ __launch_bounds__(256) void cvt_inputs(
    const float* __restrict__ q, const float* __restrict__ k, const float* __restrict__ v,
    unsigned short* __restrict__ qb16, unsigned short* __restrict__ kb16,
    unsigned short* __restrict__ vb16)
{
    const int z = blockIdx.y;
    const float* x = (z == 0) ? q : (z == 1) ? k : v;
    unsigned short* o = (z == 0) ? qb16 : (z == 1) ? kb16 : vb16;
    size_t f = ((size_t)blockIdx.x * 256 + threadIdx.x) * 8;
    float4 v0 = *(const float4*)(x + f);
    float4 v1 = *(const float4*)(x + f + 4);
    float val[8] = {v0.x, v0.y, v0.z, v0.w, v1.x, v1.y, v1.z, v1.w};
    unsigned short hi[8];
    #pragma unroll
    for (int j = 0; j < 8; ++j) hi[j] = f2bf(val[j]);
    *(uint4*)(o + f) = *(uint4*)hi;
}

// ---------------------------------------------------------------------------
// weight transpose+convert (fused): z = 0..3 -> WT bf16 [1024][1024] (n-major)
// ---------------------------------------------------------------------------
__global__ __launch_bounds__(256) void cvt_w(
    const float* __restrict__ Wq, const float* __restrict__ Wk,
    const float* __restrict__ Wv, const float* __restrict__ Wo,
    unsigned short* __restrict__ WqT, unsigned short* __restrict__ WkT,
    unsigned short* __restrict__ WvT, unsigned short* __restrict__ WoT)
{
    const int z = blockIdx.z;
    const float* W = (z == 0) ? Wq : (z == 1) ? Wk : (z == 2) ? Wv : Wo;
    unsigned short* WT = (z == 0) ? WqT : (z == 1) ? WkT : (z == 2) ? WvT : WoT;

    const int k0 = blockIdx.x * 64, n0 = blockIdx.y * 64;
    __shared__ float T[64][65];
    const int t = threadIdx.x;
    const int r = t >> 2, cc = (t & 3) * 16;
    {
        const float* src = W + (size_t)(k0 + r) * 1024 + n0 + cc;
        #pragma unroll
        for (int j = 0; j < 4; ++j) {
            float4 a = *(const float4*)(src + 4 * j);
            T[r][cc + 4 * j + 0] = a.x; T[r][cc + 4 * j + 1] = a.y;
            T[r][cc + 4 * j + 2] = a.z; T[r][cc + 4 * j + 3] = a.w;
        }
    }
    __syncthreads();
    const int d = t >> 2;
    unsigned short hi[16];
    #pragma unroll
    for (int j = 0; j < 16; ++j) hi[j] = f2bf(T[cc + j][d]);
    unsigned short* dst = WT + (size_t)(n0 + d) * 1024 + k0 + cc;
    *(uint4*)dst       = *(uint4*)hi;
    *(uint4*)(dst + 8) = *(uint4*)(hi + 8);
}

// ---------------------------------------------------------------------------
// MFMA GEMM core: 128x128 tile, BK=64, 4 waves (2x2), XOR-swizzled LDS.
// Staging via global_load_lds DMA (m97 pattern: 2 barriers per K-step,
// no VGPR round-trip). Read side unchanged.
// ---------------------------------------------------------------------------
__device__ __forceinline__ void gemm_core(
    const unsigned short* __restrict__ A, const unsigned short* __restrict__ BT,
    int Kc, unsigned short* Atile, unsigned short* Btile,
    f32x4 (&acc)[4][4], int rowBase, int colBase, int tid, int lane, int wm, int wn)
{
    #pragma unroll
    for (int mt = 0; mt < 4; ++mt)
        #pragma unroll
        for (int nt = 0; nt < 4; ++nt) {
            acc[mt][nt].x = 0.f; acc[mt][nt].y = 0.f;
            acc[mt][nt].z = 0.f; acc[mt][nt].w = 0.f;
        }
    const int wave = tid >> 6;
    const int nk = Kc >> 6;

    for (int t = 0; t < nk; ++t) {
        __syncthreads();
#if HAVE_GLOAD_LDS
        #pragma unroll
        for (int j = 0; j < 4; ++j) {
            int seg = j * 4 + wave;                  // 0..15 (1KB segments)
            int Ab  = (seg << 10) + lane * 16;       // linear LDS byte addr
            int row = Ab >> 7, off = Ab & 127;
            int sb  = off ^ ((row & 7) << 4);        // pre-swizzled source byte
            gload16(A  + (size_t)(rowBase + row) * Kc + t * 64 + (sb >> 1),
                    (char*)Atile + (seg << 10));
            gload16(BT + (size_t)(colBase + row) * Kc + t * 64 + (sb >> 1),
                    (char*)Btile + (seg << 10));
        }
#else
        {
            const int srow = tid >> 3, sch = tid & 7;
            #pragma unroll
            for (int i = 0; i < 4; ++i) {
                int row = srow + i * 32;
                int off = row * 128 + ((sch * 16) ^ ((row & 7) << 4));
                *(uint4*)((char*)Atile + off) =
                    *(const uint4*)(A  + (size_t)(rowBase + row) * Kc + t * 64 + sch * 8);
                *(uint4*)((char*)Btile + off) =
                    *(const uint4*)(BT + (size_t)(colBase + row) * Kc + t * 64 + sch * 8);
            }
        }
#endif
        __syncthreads();

        bf16x8 a0[4], a1[4];
        const int g = (lane >> 4) * 16;
        #pragma unroll
        for (int mt = 0; mt < 4; ++mt) {
            int arow = wm + mt * 16 + (lane & 15);
            const char* base = (const char*)Atile + arow * 128;
            int sw = (arow & 7) << 4;
            a0[mt] = *(const bf16x8*)(base + (g ^ sw));
            a1[mt] = *(const bf16x8*)(base + ((g + 64) ^ sw));
        }
        #pragma unroll
        for (int nt = 0; nt < 4; ++nt) {
            int brow = wn + nt * 16 + (lane & 15);
            const char* base = (const char*)Btile + brow * 128;
            int sw = (brow & 7) << 4;
            bf16x8 b0 = *(const bf16x8*)(base + (g ^ sw));
            bf16x8 b1 = *(const bf16x8*)(base + ((g + 64) ^ sw));
            #pragma unroll
            for (int mt = 0; mt < 4; ++mt) {
                acc[mt][nt] = MFMA16(a0[mt], b0, acc[mt][nt]);
                acc[mt][nt] = MFMA16(a1[mt], b1, acc[mt][nt]);
            }
        }
    }
}

// fused QKV projections, all K=1024: z=0 Q(*0.125)->qbb, z=1 K->kbb,
// z=2 V->vbT[b][h][d][c] (fused transpose epilogue)
__global__ __launch_bounds__(256) void gemm_qkv(
    const unsigned short* __restrict__ qb16, const unsigned short* __restrict__ kb16,
    const unsigned short* __restrict__ vb16,
    const unsigned short* __restrict__ WqT, const unsigned short* __restrict__ WkT,
    const unsigned short* __restrict__ WvT,
    const float* __restrict__ bq, const float* __restrict__ bk,
    const float* __restrict__ bv,
    unsigned short* __restrict__ qbb, unsigned short* __restrict__ kbb,
    unsigned short* __restrict__ vbT)
{
    __shared__ unsigned short Atile[128 * 64];
    __shared__ unsigned short Btile[128 * 64];
    const int z = blockIdx.z;
    const unsigned short* A  = (z == 0) ? qb16 : (z == 1) ? kb16 : vb16;
    const unsigned short* BT = (z == 0) ? WqT  : (z == 1) ? WkT  : WvT;
    const float* bias        = (z == 0) ? bq   : (z == 1) ? bk   : bv;
    const float scale        = (z == 0) ? 0.125f : 1.0f;

    const int tid  = threadIdx.x;
    const int lane = tid & 63;
    const int wave = tid >> 6;
    const int wm = (wave >> 1) * 64;
    const int wn = (wave & 1) * 64;
    const int rowBase = blockIdx.y * 128;
    const int colBase = blockIdx.x * 128;

    f32x4 acc[4][4];
    gemm_core(A, BT, 1024, Atile, Btile, acc, rowBase, colBase, tid, lane, wm, wn);

    const int gg = lane >> 4;
    #pragma unroll
    for (int nt = 0; nt < 4; ++nt) {
        int col = colBase + wn + nt * 16 + (lane & 15);
        float bv_ = bias[col];
        if (z == 2) {
            int h = col >> 6, d = col & 63;
            #pragma unroll
            for (int mt = 0; mt < 4; ++mt) {
                int row0 = rowBase + wm + mt * 16 + gg * 4;
                int bb_ = row0 >> 11, cc = row0 & 2047;
                unsigned long long pk =
                      (unsigned long long)f2bf(acc[mt][nt][0] + bv_)
                    | ((unsigned long long)f2bf(acc[mt][nt][1] + bv_) << 16)
                    | ((unsigned long long)f2bf(acc[mt][nt][2] + bv_) << 32)
                    | ((unsigned long long)f2bf(acc[mt][nt][3] + bv_) << 48);
                *(unsigned long long*)(vbT +
                    (((size_t)((bb_ * NHEAD + h) * DEPTH + d)) << 11) + cc) = pk;
            }
        } else {
            unsigned short* C = (z == 0) ? qbb : kbb;
            #pragma unroll
            for (int mt = 0; mt < 4; ++mt) {
                #pragma unroll
                for (int r = 0; r < 4; ++r) {
                    int row = rowBase + wm + mt * 16 + gg * 4 + r;
                    C[(size_t)row * 1024 + col] = f2bf((acc[mt][nt][r] + bv_) * scale);
                }
            }
        }
    }
}

// output projection: f32 out
__global__ __launch_bounds__(256) void gemm_out(
    const unsigned short* __restrict__ A, const unsigned short* __restrict__ BT,
    const float* __restrict__ bias, float* __restrict__ C)
{
    __shared__ unsigned short Atile[128 * 64];
    __shared__ unsigned short Btile[128 * 64];
    const int tid  = threadIdx.x;
    const int lane = tid & 63;
    const int wave = tid >> 6;
    const int wm = (wave >> 1) * 64;
    const int wn = (wave & 1) * 64;
    const int rowBase = blockIdx.y * 128;
    const int colBase = blockIdx.x * 128;

    f32x4 acc[4][4];
    gemm_core(A, BT, 1024, Atile, Btile, acc, rowBase, colBase, tid, lane, wm, wn);

    const int gg = lane >> 4;
    #pragma unroll
    for (int nt = 0; nt < 4; ++nt) {
        int col = colBase + wn + nt * 16 + (lane & 15);
        float bv_ = bias[col];
        #pragma unroll
        for (int mt = 0; mt < 4; ++mt) {
            #pragma unroll
            for (int r = 0; r < 4; ++r) {
                int row = rowBase + wm + mt * 16 + gg * 4 + r;
                C[(size_t)row * 1024 + col] = acc[mt][nt][r] + bv_;
            }
        }
    }
}

// ---------------------------------------------------------------------------
// stage a 64x64 bf16 tile into LDS: global_load_lds DMA with pre-swizzled
// source (identical final LDS contents as the old reg-staged XOR writes).
// ---------------------------------------------------------------------------
__device__ __forceinline__ void stage64x64(
    unsigned short* dst, const unsigned short* __restrict__ src,
    int srcStride, int wave, int lane, int tid)
{
#if HAVE_GLOAD_LDS
    #pragma unroll
    for (int j = 0; j < 2; ++j) {
        int seg = j * 4 + wave;                  // 0..7 (1KB segments)
        int Ab  = (seg << 10) + lane * 16;
        int row = Ab >> 7, off = Ab & 127;
        int sb  = off ^ ((row & 7) << 4);
        gload16(src + (size_t)row * srcStride + (sb >> 1), (char*)dst + (seg << 10));
    }
#else
    #pragma unroll
    for (int t = tid; t < 512; t += 256) {
        int row = t >> 3, ch = t & 7;
        uint4 v = *(const uint4*)(src + (size_t)row * srcStride + ch * 8);
        *(uint4*)((char*)dst + row * 128 + ((ch * 16) ^ ((row & 7) << 4))) = v;
    }
#endif
}

// ---------------------------------------------------------------------------
// MFMA attention (R14 = R8 structure + NT stores, arithmetic frozen).
// Delta vs R14: staging via global_load_lds DMA (no VGPR round-trip).
// ---------------------------------------------------------------------------
__global__ __launch_bounds__(256) void attn_mfma(
    const unsigned short* __restrict__ qb, const unsigned short* __restrict__ kb,
    const unsigned short* __restrict__ vbT,
    float* __restrict__ attn, unsigned short* __restrict__ ctxb)
{
    const int tid  = threadIdx.x;
    const int lane = tid & 63;
    const int wave = tid >> 6;
    const int qt = blockIdx.x, h = blockIdx.y, b = blockIdx.z;
    const int i0 = qt * 64;

    __shared__ unsigned short K_lds[64 * 64];
    __shared__ unsigned short V_lds[64 * 64];
    __shared__ unsigned short P_lds[4][16 * 64];
    __shared__ unsigned long long bmask[32];

    if (tid < 32) {
        unsigned long long w = 0;
        for (int j = 0; j < 64; ++j) {
            int d = tid * 64 + j;
            bool a = false;
            #pragma unroll
            for (int bb = 0; bb < NBANDS; ++bb)
                a = a || (d >= cBLO[bb] && d <= cBHI[bb]);
            if (a) w |= (1ull << j);
        }
        bmask[tid] = w;
    }

    unsigned int amask = 0;
    for (int ch = 0; ch < 32; ++ch) {
        int c0 = ch * 64;
        bool act = false;
        #pragma unroll
        for (int bb = 0; bb < NBANDS; ++bb)
            act = act || ((c0 <= i0 + 63 - cBLO[bb]) && (c0 + 63 >= i0 - cBHI[bb]));
        if (act) amask |= (1u << ch);
    }

    float* ablock = attn + ((size_t)((b * NHEAD + h) * SEQ)) * SEQ;

    // zero chunks up front: fire-and-forget non-temporal burst, overlaps pass 1
    for (int ch = 0; ch < 32; ++ch) {
        if ((amask >> ch) & 1u) continue;
        const int c0 = ch * 64;
        f32x4 z = {0.f, 0.f, 0.f, 0.f};
        #pragma unroll
        for (int rr = 0; rr < 4; ++rr) {
            int i = i0 + wave * 16 + rr * 4 + (lane >> 4);
            __builtin_nontemporal_store(z,
                (f32x4*)(ablock + (size_t)i * SEQ + c0 + (lane & 15) * 4));
        }
    }

    const int qrow = i0 + wave * 16 + (lane & 15);
    const unsigned short* qptr =
        qb + ((size_t)(b * SEQ + qrow)) * DMODEL + h * DEPTH + (lane >> 4) * 8;
    bf16x8 qa0 = *(const bf16x8*)qptr;
    bf16x8 qa1 = *(const bf16x8*)(qptr + 32);

    const int rgrp = (lane >> 4) << 2;
    const int ibase = i0 + wave * 16 + rgrp;

    // ---------------- pass 1: row sums ----------------
    float rsum[4] = {0.f, 0.f, 0.f, 0.f};
    for (int ch = 0; ch < 32; ++ch) {
        if (!((amask >> ch) & 1u)) continue;
        const int c0 = ch * 64;
        __syncthreads();
        stage64x64(K_lds, kb + ((size_t)(b * SEQ + c0)) * DMODEL + h * DEPTH, DMODEL, wave, lane, tid);
        __syncthreads();

        f32x4 s[4];
        #pragma unroll
        for (int nt = 0; nt < 4; ++nt) { s[nt].x = 0.f; s[nt].y = 0.f; s[nt].z = 0.f; s[nt].w = 0.f; }
        #pragma unroll
        for (int nt = 0; nt < 4; ++nt) {
            int krow = nt * 16 + (lane & 15);
            const char* kbase = (const char*)K_lds + krow * 128;
            int sw = (krow & 7) << 4;
            bf16x8 b0 = *(const bf16x8*)(kbase + ((((lane >> 4) * 16) + 0) ^ sw));
            bf16x8 b1 = *(const bf16x8*)(kbase + ((((lane >> 4) * 16) + 64) ^ sw));
            s[nt] = MFMA16(qa0, b0, s[nt]);
            s[nt] = MFMA16(qa1, b1, s[nt]);
        }
        #pragma unroll
        for (int nt = 0; nt < 4; ++nt) {
            int c = c0 + nt * 16 + (lane & 15);
            #pragma unroll
            for (int r = 0; r < 4; ++r) {
                int d = ibase + r - c;
                float e = 0.f;
                if (d >= 0 && ((bmask[d >> 6] >> (d & 63)) & 1ull))
                    e = __expf(s[nt][r]);
                rsum[r] += e;
            }
        }
    }
    #pragma unroll
    for (int r = 0; r < 4; ++r) {
        float v = rsum[r];
        v += __shfl_xor(v, 1); v += __shfl_xor(v, 2);
        v += __shfl_xor(v, 4); v += __shfl_xor(v, 8);
        rsum[r] = 1.0f / v;
    }

    // ---------------- pass 2: attn write + PV ----------------
    f32x4 o[4];
    #pragma unroll
    for (int nt = 0; nt < 4; ++nt) { o[nt].x = 0.f; o[nt].y = 0.f; o[nt].z = 0.f; o[nt].w = 0.f; }

    for (int ch = 0; ch < 32; ++ch) {
        const int c0 = ch * 64;
        if (!((amask >> ch) & 1u)) continue;   // zeros already written
        __syncthreads();
        stage64x64(K_lds, kb + ((size_t)(b * SEQ + c0)) * DMODEL + h * DEPTH, DMODEL, wave, lane, tid);
        stage64x64(V_lds, vbT + ((size_t)((b * NHEAD + h) * DEPTH)) * SEQ + c0, SEQ, wave, lane, tid);
        __syncthreads();

        f32x4 s[4];
        #pragma unroll
        for (int nt = 0; nt < 4; ++nt) { s[nt].x = 0.f; s[nt].y = 0.f; s[nt].z = 0.f; s[nt].w = 0.f; }
        #pragma unroll
        for (int nt = 0; nt < 4; ++nt) {
            int krow = nt * 16 + (lane & 15);
            const char* kbase = (const char*)K_lds + krow * 128;
            int sw = (krow & 7) << 4;
            bf16x8 b0 = *(const bf16x8*)(kbase + ((((lane >> 4) * 16) + 0) ^ sw));
            bf16x8 b1 = *(const bf16x8*)(kbase + ((((lane >> 4) * 16) + 64) ^ sw));
            s[nt] = MFMA16(qa0, b0, s[nt]);
            s[nt] = MFMA16(qa1, b1, s[nt]);
        }

        char* pwav = (char*)&P_lds[wave][0];
        #pragma unroll
        for (int nt = 0; nt < 4; ++nt) {
            int c = c0 + nt * 16 + (lane & 15);
            #pragma unroll
            for (int r = 0; r < 4; ++r) {
                int row_local = rgrp + r;
                int i = i0 + wave * 16 + row_local;
                int d = i - c;
                float e = 0.f;
                if (d >= 0 && ((bmask[d >> 6] >> (d & 63)) & 1ull))
                    e = __expf(s[nt][r]) * rsum[r];
                __builtin_nontemporal_store(e, ablock + (size_t)i * SEQ + c);
                int colb = (nt * 16 + (lane & 15)) * 2;
                *(unsigned short*)(pwav + row_local * 128 + (colb ^ ((row_local & 7) << 4))) = f2bf(e);
            }
        }
        const char* pbase = (const char*)&P_lds[wave][0] + (lane & 15) * 128;
        int swp = ((lane & 15) & 7) << 4;
        bf16x8 pa0 = *(const bf16x8*)(pbase + ((((lane >> 4) * 16) + 0) ^ swp));
        bf16x8 pa1 = *(const bf16x8*)(pbase + ((((lane >> 4) * 16) + 64) ^ swp));
        #pragma unroll
        for (int nt = 0; nt < 4; ++nt) {
            int vrow = nt * 16 + (lane & 15);
            const char* vbase = (const char*)V_lds + vrow * 128;
            int sw = (vrow & 7) << 4;
            bf16x8 b0 = *(const bf16x8*)(vbase + ((((lane >> 4) * 16) + 0) ^ sw));
            bf16x8 b1 = *(const bf16x8*)(vbase + ((((lane >> 4) * 16) + 64) ^ sw));
            o[nt] = MFMA16(pa0, b0, o[nt]);
            o[nt] = MFMA16(pa1, b1, o[nt]);
        }
    }

    // ---------------- ctx store (bf16) ----------------
    #pragma unroll
    for (int nt = 0; nt < 4; ++nt) {
        int d = nt * 16 + (lane & 15);
        #pragma unroll
        for (int r = 0; r < 4; ++r) {
            int i = i0 + wave * 16 + rgrp + r;
            ctxb[((size_t)(b * SEQ + i)) * DMODEL + h * DEPTH + d] = f2bf(o[nt][r]);
        }
    }
}

// ---------------------------------------------------------------------------
extern "C" void kernel_launch(void* const* d_in, const int* in_sizes, int n_in,
                              void* d_out, int out_size, void* d_ws, size_t ws_size,
                              hipStream_t stream) {
    const float* v  = (const float*)d_in[0];
    const float* k  = (const float*)d_in[1];
    const float* q  = (const float*)d_in[2];
    const float* Wq = (const float*)d_in[3];
    const float* bq = (const float*)d_in[4];
    const float* Wk = (const float*)d_in[5];
    const float* bk = (const float*)d_in[6];
    const float* Wv = (const float*)d_in[7];
    const float* bv = (const float*)d_in[8];
    const float* Wo = (const float*)d_in[9];
    const float* bo = (const float*)d_in[10];

    float* out  = (float*)d_out;                   // [B*S, D]
    float* attn = out + 4194304;                   // [B, H, S, S]  (512 MB)

    // --- d_ws layout (34 MB) — everything that must survive attn_mfma ---
    unsigned short* qbb  = (unsigned short*)d_ws;            // 8 MB bf16
    unsigned short* kbb  = qbb  + 4194304;                   // 8 MB
    unsigned short* vbT  = kbb  + 4194304;                   // 8 MB
    unsigned short* ctxb = vbT  + 4194304;                   // 8 MB
    unsigned short* WoT  = ctxb + 4194304;                   // 2 MB

    // --- scratch inside attn region (dead before attn_mfma writes it) ---
    unsigned short* qb16 = (unsigned short*)attn;            // 8 MB
    unsigned short* kb16 = qb16 + 4194304;                   // 8 MB
    unsigned short* vb16 = kb16 + 4194304;                   // 8 MB
    unsigned short* WqT  = vb16 + 4194304;                   // 2 MB
    unsigned short* WkT  = WqT  + 1048576;                   // 2 MB
    unsigned short* WvT  = WkT  + 1048576;                   // 2 MB

    cvt_inputs<<<dim3(2048, 3), 256, 0, stream>>>(q, k, v, qb16, kb16, vb16);
    cvt_w<<<dim3(16, 16, 4), 256, 0, stream>>>(Wq, Wk, Wv, Wo, WqT, WkT, WvT, WoT);

    // fused QKV projections, all K=1024 (768 blocks = 3/CU)
    gemm_qkv<<<dim3(8, 32, 3), 256, 0, stream>>>(
        qb16, kb16, vb16, WqT, WkT, WvT, bq, bk, bv, qbb, kbb, vbT);

    attn_mfma<<<dim3(SEQ / 64, NHEAD, BATCH), 256, 0, stream>>>(qbb, kbb, vbT, attn, ctxb);

    gemm_out<<<dim3(8, 32), 256, 0, stream>>>(ctxb, WoT, bo, out);
}

// Round 16
// 251.096 us; speedup vs baseline: 1.7367x; 1.0184x over previous
//
#include <hip/hip_runtime.h>
#include <hip/hip_bf16.h>

#define BATCH 2
#define SEQ   2048
#define DMODEL 1024
#define NHEAD 16
#define DEPTH 64
#define NBANDS 7

// Allowed diffs: causal AND (local<=32 OR |log2(d)-round|<0.1), derived exactly:
//   [0,34] [60,68] [120,137] [239,274] [478,548] [956,1097] [1911,2047]
__device__ __constant__ int cBLO[NBANDS] = {0, 60, 120, 239, 478, 956, 1911};
__device__ __constant__ int cBHI[NBANDS] = {34, 68, 137, 274, 548, 1097, 2047};

typedef __attribute__((ext_vector_type(4))) float f32x4;
typedef __attribute__((ext_vector_type(8))) short bf16x8;
#define MFMA16(a, b, c) __builtin_amdgcn_mfma_f32_16x16x32_bf16(a, b, c, 0, 0, 0)

__device__ __forceinline__ unsigned short f2bf(float x) {
    unsigned int u = __float_as_uint(x);
    u += 0x7fffu + ((u >> 16) & 1u);   // RNE
    return (unsigned short)(u >> 16);
}

// ---------------------------------------------------------------------------
// async global->LDS 16B DMA. LDS dest LINEAR (rule #21); XOR swizzle applied
// to the per-lane GLOBAL source address (same involution as the read side).
// ---------------------------------------------------------------------------
#if __has_builtin(__builtin_amdgcn_global_load_lds)
#define HAVE_GLOAD_LDS 1
__device__ __forceinline__ void gload16(const void* g, void* lds) {
    __builtin_amdgcn_global_load_lds(
        (const __attribute__((address_space(1))) unsigned int*)(unsigned long long)g,
        (__attribute__((address_space(3))) unsigned int*)(unsigned int)(unsigned long long)lds,
        16, 0, 0);
}
#else
#define HAVE_GLOAD_LDS 0
#endif

// ---------------------------------------------------------------------------
// input converts (fused): z=0 q, z=1 k, z=2 v  ->  plain bf16 [4096][1024]
// ---------------------------------------------------------------------------
__global__ __launch_bounds__(256) void cvt_inputs(
    const float* __restrict__ q, const float* __restrict__ k, const float* __restrict__ v,
    unsigned short* __restrict__ qb16, unsigned short* __restrict__ kb16,
    unsigned short* __restrict__ vb16)
{
    const int z = blockIdx.y;
    const float* x = (z == 0) ? q : (z == 1) ? k : v;
    unsigned short* o = (z == 0) ? qb16 : (z == 1) ? kb16 : vb16;
    size_t f = ((size_t)blockIdx.x * 256 + threadIdx.x) * 8;
    float4 v0 = *(const float4*)(x + f);
    float4 v1 = *(const float4*)(x + f + 4);
    float val[8] = {v0.x, v0.y, v0.z, v0.w, v1.x, v1.y, v1.z, v1.w};
    unsigned short hi[8];
    #pragma unroll
    for (int j = 0; j < 8; ++j) hi[j] = f2bf(val[j]);
    *(uint4*)(o + f) = *(uint4*)hi;
}

// ---------------------------------------------------------------------------
// weight transpose+convert (fused): z = 0..3 -> WT bf16 [1024][1024] (n-major)
// ---------------------------------------------------------------------------
__global__ __launch_bounds__(256) void cvt_w(
    const float* __restrict__ Wq, const float* __restrict__ Wk,
    const float* __restrict__ Wv, const float* __restrict__ Wo,
    unsigned short* __restrict__ WqT, unsigned short* __restrict__ WkT,
    unsigned short* __restrict__ WvT, unsigned short* __restrict__ WoT)
{
    const int z = blockIdx.z;
    const float* W = (z == 0) ? Wq : (z == 1) ? Wk : (z == 2) ? Wv : Wo;
    unsigned short* WT = (z == 0) ? WqT : (z == 1) ? WkT : (z == 2) ? WvT : WoT;

    const int k0 = blockIdx.x * 64, n0 = blockIdx.y * 64;
    __shared__ float T[64][65];
    const int t = threadIdx.x;
    const int r = t >> 2, cc = (t & 3) * 16;
    {
        const float* src = W + (size_t)(k0 + r) * 1024 + n0 + cc;
        #pragma unroll
        for (int j = 0; j < 4; ++j) {
            float4 a = *(const float4*)(src + 4 * j);
            T[r][cc + 4 * j + 0] = a.x; T[r][cc + 4 * j + 1] = a.y;
            T[r][cc + 4 * j + 2] = a.z; T[r][cc + 4 * j + 3] = a.w;
        }
    }
    __syncthreads();
    const int d = t >> 2;
    unsigned short hi[16];
    #pragma unroll
    for (int j = 0; j < 16; ++j) hi[j] = f2bf(T[cc + j][d]);
    unsigned short* dst = WT + (size_t)(n0 + d) * 1024 + k0 + cc;
    *(uint4*)dst       = *(uint4*)hi;
    *(uint4*)(dst + 8) = *(uint4*)(hi + 8);
}

// ---------------------------------------------------------------------------
// MFMA GEMM core: 128x128 tile, BK=64, 4 waves (2x2), XOR-swizzled LDS.
// Staging via global_load_lds DMA.
// ---------------------------------------------------------------------------
__device__ __forceinline__ void gemm_core(
    const unsigned short* __restrict__ A, const unsigned short* __restrict__ BT,
    int Kc, unsigned short* Atile, unsigned short* Btile,
    f32x4 (&acc)[4][4], int rowBase, int colBase, int tid, int lane, int wm, int wn)
{
    #pragma unroll
    for (int mt = 0; mt < 4; ++mt)
        #pragma unroll
        for (int nt = 0; nt < 4; ++nt) {
            acc[mt][nt].x = 0.f; acc[mt][nt].y = 0.f;
            acc[mt][nt].z = 0.f; acc[mt][nt].w = 0.f;
        }
    const int wave = tid >> 6;
    const int nk = Kc >> 6;

    for (int t = 0; t < nk; ++t) {
        __syncthreads();
#if HAVE_GLOAD_LDS
        #pragma unroll
        for (int j = 0; j < 4; ++j) {
            int seg = j * 4 + wave;
            int Ab  = (seg << 10) + lane * 16;
            int row = Ab >> 7, off = Ab & 127;
            int sb  = off ^ ((row & 7) << 4);
            gload16(A  + (size_t)(rowBase + row) * Kc + t * 64 + (sb >> 1),
                    (char*)Atile + (seg << 10));
            gload16(BT + (size_t)(colBase + row) * Kc + t * 64 + (sb >> 1),
                    (char*)Btile + (seg << 10));
        }
#else
        {
            const int srow = tid >> 3, sch = tid & 7;
            #pragma unroll
            for (int i = 0; i < 4; ++i) {
                int row = srow + i * 32;
                int off = row * 128 + ((sch * 16) ^ ((row & 7) << 4));
                *(uint4*)((char*)Atile + off) =
                    *(const uint4*)(A  + (size_t)(rowBase + row) * Kc + t * 64 + sch * 8);
                *(uint4*)((char*)Btile + off) =
                    *(const uint4*)(BT + (size_t)(colBase + row) * Kc + t * 64 + sch * 8);
            }
        }
#endif
        __syncthreads();

        bf16x8 a0[4], a1[4];
        const int g = (lane >> 4) * 16;
        #pragma unroll
        for (int mt = 0; mt < 4; ++mt) {
            int arow = wm + mt * 16 + (lane & 15);
            const char* base = (const char*)Atile + arow * 128;
            int sw = (arow & 7) << 4;
            a0[mt] = *(const bf16x8*)(base + (g ^ sw));
            a1[mt] = *(const bf16x8*)(base + ((g + 64) ^ sw));
        }
        #pragma unroll
        for (int nt = 0; nt < 4; ++nt) {
            int brow = wn + nt * 16 + (lane & 15);
            const char* base = (const char*)Btile + brow * 128;
            int sw = (brow & 7) << 4;
            bf16x8 b0 = *(const bf16x8*)(base + (g ^ sw));
            bf16x8 b1 = *(const bf16x8*)(base + ((g + 64) ^ sw));
            #pragma unroll
            for (int mt = 0; mt < 4; ++mt) {
                acc[mt][nt] = MFMA16(a0[mt], b0, acc[mt][nt]);
                acc[mt][nt] = MFMA16(a1[mt], b1, acc[mt][nt]);
            }
        }
    }
}

// fused QKV projections, all K=1024: z=0 Q(*0.125)->qbb, z=1 K->kbb,
// z=2 V->vbT[b][h][d][c] (fused transpose epilogue)
__global__ __launch_bounds__(256) void gemm_qkv(
    const unsigned short* __restrict__ qb16, const unsigned short* __restrict__ kb16,
    const unsigned short* __restrict__ vb16,
    const unsigned short* __restrict__ WqT, const unsigned short* __restrict__ WkT,
    const unsigned short* __restrict__ WvT,
    const float* __restrict__ bq, const float* __restrict__ bk,
    const float* __restrict__ bv,
    unsigned short* __restrict__ qbb, unsigned short* __restrict__ kbb,
    unsigned short* __restrict__ vbT)
{
    __shared__ unsigned short Atile[128 * 64];
    __shared__ unsigned short Btile[128 * 64];
    const int z = blockIdx.z;
    const unsigned short* A  = (z == 0) ? qb16 : (z == 1) ? kb16 : vb16;
    const unsigned short* BT = (z == 0) ? WqT  : (z == 1) ? WkT  : WvT;
    const float* bias        = (z == 0) ? bq   : (z == 1) ? bk   : bv;
    const float scale        = (z == 0) ? 0.125f : 1.0f;

    const int tid  = threadIdx.x;
    const int lane = tid & 63;
    const int wave = tid >> 6;
    const int wm = (wave >> 1) * 64;
    const int wn = (wave & 1) * 64;
    const int rowBase = blockIdx.y * 128;
    const int colBase = blockIdx.x * 128;

    f32x4 acc[4][4];
    gemm_core(A, BT, 1024, Atile, Btile, acc, rowBase, colBase, tid, lane, wm, wn);

    const int gg = lane >> 4;
    #pragma unroll
    for (int nt = 0; nt < 4; ++nt) {
        int col = colBase + wn + nt * 16 + (lane & 15);
        float bv_ = bias[col];
        if (z == 2) {
            int h = col >> 6, d = col & 63;
            #pragma unroll
            for (int mt = 0; mt < 4; ++mt) {
                int row0 = rowBase + wm + mt * 16 + gg * 4;
                int bb_ = row0 >> 11, cc = row0 & 2047;
                unsigned long long pk =
                      (unsigned long long)f2bf(acc[mt][nt][0] + bv_)
                    | ((unsigned long long)f2bf(acc[mt][nt][1] + bv_) << 16)
                    | ((unsigned long long)f2bf(acc[mt][nt][2] + bv_) << 32)
                    | ((unsigned long long)f2bf(acc[mt][nt][3] + bv_) << 48);
                *(unsigned long long*)(vbT +
                    (((size_t)((bb_ * NHEAD + h) * DEPTH + d)) << 11) + cc) = pk;
            }
        } else {
            unsigned short* C = (z == 0) ? qbb : kbb;
            #pragma unroll
            for (int mt = 0; mt < 4; ++mt) {
                #pragma unroll
                for (int r = 0; r < 4; ++r) {
                    int row = rowBase + wm + mt * 16 + gg * 4 + r;
                    C[(size_t)row * 1024 + col] = f2bf((acc[mt][nt][r] + bv_) * scale);
                }
            }
        }
    }
}

// output projection: f32 out
__global__ __launch_bounds__(256) void gemm_out(
    const unsigned short* __restrict__ A, const unsigned short* __restrict__ BT,
    const float* __restrict__ bias, float* __restrict__ C)
{
    __shared__ unsigned short Atile[128 * 64];
    __shared__ unsigned short Btile[128 * 64];
    const int tid  = threadIdx.x;
    const int lane = tid & 63;
    const int wave = tid >> 6;
    const int wm = (wave >> 1) * 64;
    const int wn = (wave & 1) * 64;
    const int rowBase = blockIdx.y * 128;
    const int colBase = blockIdx.x * 128;

    f32x4 acc[4][4];
    gemm_core(A, BT, 1024, Atile, Btile, acc, rowBase, colBase, tid, lane, wm, wn);

    const int gg = lane >> 4;
    #pragma unroll
    for (int nt = 0; nt < 4; ++nt) {
        int col = colBase + wn + nt * 16 + (lane & 15);
        float bv_ = bias[col];
        #pragma unroll
        for (int mt = 0; mt < 4; ++mt) {
            #pragma unroll
            for (int r = 0; r < 4; ++r) {
                int row = rowBase + wm + mt * 16 + gg * 4 + r;
                C[(size_t)row * 1024 + col] = acc[mt][nt][r] + bv_;
            }
        }
    }
}

// ---------------------------------------------------------------------------
// stage a 64x64 bf16 tile into LDS: global_load_lds DMA with pre-swizzled src
// ---------------------------------------------------------------------------
__device__ __forceinline__ void stage64x64(
    unsigned short* dst, const unsigned short* __restrict__ src,
    int srcStride, int wave, int lane, int tid)
{
#if HAVE_GLOAD_LDS
    #pragma unroll
    for (int j = 0; j < 2; ++j) {
        int seg = j * 4 + wave;
        int Ab  = (seg << 10) + lane * 16;
        int row = Ab >> 7, off = Ab & 127;
        int sb  = off ^ ((row & 7) << 4);
        gload16(src + (size_t)row * srcStride + (sb >> 1), (char*)dst + (seg << 10));
    }
#else
    #pragma unroll
    for (int t = tid; t < 512; t += 256) {
        int row = t >> 3, ch = t & 7;
        uint4 v = *(const uint4*)(src + (size_t)row * srcStride + ch * 8);
        *(uint4*)((char*)dst + row * 128 + ((ch * 16) ^ ((row & 7) << 4))) = v;
    }
#endif
}

// ---------------------------------------------------------------------------
// MFMA attention, SWAPPED QK^T (S^T = K·Q^T): each lane owns ONE q-row
// (lane&15) and 4 CONSECUTIVE k-cols per fragment -> f32x4 NT attn stores
// (4x fewer store instrs), b64 P_lds writes, rsum entirely lane-local.
// P is normalized before PV, so ctx needs no cross-lane rsinv (R5 bug class
// structurally absent). K/V staging, LDS layouts, mask tables: unchanged.
// ---------------------------------------------------------------------------
__global__ __launch_bounds__(256) void attn_mfma(
    const unsigned short* __restrict__ qb, const unsigned short* __restrict__ kb,
    const unsigned short* __restrict__ vbT,
    float* __restrict__ attn, unsigned short* __restrict__ ctxb)
{
    const int tid  = threadIdx.x;
    const int lane = tid & 63;
    const int wave = tid >> 6;
    const int g    = lane >> 4;          // 0..3
    const int qt = blockIdx.x, h = blockIdx.y, b = blockIdx.z;
    const int i0 = qt * 64;

    __shared__ unsigned short K_lds[64 * 64];
    __shared__ unsigned short V_lds[64 * 64];
    __shared__ unsigned short P_lds[4][16 * 64];
    __shared__ unsigned long long bmask[32];

    if (tid < 32) {
        unsigned long long w = 0;
        for (int j = 0; j < 64; ++j) {
            int d = tid * 64 + j;
            bool a = false;
            #pragma unroll
            for (int bb = 0; bb < NBANDS; ++bb)
                a = a || (d >= cBLO[bb] && d <= cBHI[bb]);
            if (a) w |= (1ull << j);
        }
        bmask[tid] = w;
    }

    unsigned int amask = 0;
    for (int ch = 0; ch < 32; ++ch) {
        int c0 = ch * 64;
        bool act = false;
        #pragma unroll
        for (int bb = 0; bb < NBANDS; ++bb)
            act = act || ((c0 <= i0 + 63 - cBLO[bb]) && (c0 + 63 >= i0 - cBHI[bb]));
        if (act) amask |= (1u << ch);
    }

    float* ablock = attn + ((size_t)((b * NHEAD + h) * SEQ)) * SEQ;

    // zero chunks up front: fire-and-forget non-temporal burst
    for (int ch = 0; ch < 32; ++ch) {
        if ((amask >> ch) & 1u) continue;
        const int c0 = ch * 64;
        f32x4 z = {0.f, 0.f, 0.f, 0.f};
        #pragma unroll
        for (int rr = 0; rr < 4; ++rr) {
            int i = i0 + wave * 16 + rr * 4 + g;
            __builtin_nontemporal_store(z,
                (f32x4*)(ablock + (size_t)i * SEQ + c0 + (lane & 15) * 4));
        }
    }

    // this lane's q-row; Q fragments as B-operand (k-offset 8g along D)
    const int i_row = i0 + wave * 16 + (lane & 15);
    const unsigned short* qptr =
        qb + ((size_t)(b * SEQ + i_row)) * DMODEL + h * DEPTH + g * 8;
    bf16x8 qf0 = *(const bf16x8*)qptr;
    bf16x8 qf1 = *(const bf16x8*)(qptr + 32);

    float* arow = ablock + (size_t)i_row * SEQ;

    // ---------------- pass 1: row sum (lane-local) ----------------
    float rs = 0.f;
    for (int ch = 0; ch < 32; ++ch) {
        if (!((amask >> ch) & 1u)) continue;
        const int c0 = ch * 64;
        __syncthreads();
        stage64x64(K_lds, kb + ((size_t)(b * SEQ + c0)) * DMODEL + h * DEPTH, DMODEL, wave, lane, tid);
        __syncthreads();

        #pragma unroll
        for (int nt = 0; nt < 4; ++nt) {
            int krow = nt * 16 + (lane & 15);
            const char* kbase = (const char*)K_lds + krow * 128;
            int sw = (krow & 7) << 4;
            bf16x8 ka0 = *(const bf16x8*)(kbase + ((g * 16) ^ sw));
            bf16x8 ka1 = *(const bf16x8*)(kbase + ((g * 16 + 64) ^ sw));
            f32x4 s = {0.f, 0.f, 0.f, 0.f};
            s = MFMA16(ka0, qf0, s);
            s = MFMA16(ka1, qf1, s);
            #pragma unroll
            for (int r = 0; r < 4; ++r) {
                int d = i_row - (c0 + nt * 16 + g * 4 + r);
                if (d >= 0 && ((bmask[d >> 6] >> (d & 63)) & 1ull))
                    rs += __expf(s[r]);
            }
        }
    }
    // sum lanes with same (lane&15): rows live in lanes 0..15 afterwards
    rs += __shfl_xor(rs, 16);
    rs += __shfl_xor(rs, 32);
    const float rsinv = 1.0f / rs;   // row i_row; d=0 always allowed -> rs>0

    // ---------------- pass 2: attn write + PV ----------------
    f32x4 o[4];
    #pragma unroll
    for (int dt = 0; dt < 4; ++dt) { o[dt].x = 0.f; o[dt].y = 0.f; o[dt].z = 0.f; o[dt].w = 0.f; }

    char* prow = (char*)&P_lds[wave][0] + (lane & 15) * 128;
    const int swp = ((lane & 15) & 7) << 4;

    for (int ch = 0; ch < 32; ++ch) {
        const int c0 = ch * 64;
        if (!((amask >> ch) & 1u)) continue;   // zeros already written
        __syncthreads();
        stage64x64(K_lds, kb + ((size_t)(b * SEQ + c0)) * DMODEL + h * DEPTH, DMODEL, wave, lane, tid);
        stage64x64(V_lds, vbT + ((size_t)((b * NHEAD + h) * DEPTH)) * SEQ + c0, SEQ, wave, lane, tid);
        __syncthreads();

        #pragma unroll
        for (int nt = 0; nt < 4; ++nt) {
            int krow = nt * 16 + (lane & 15);
            const char* kbase = (const char*)K_lds + krow * 128;
            int sw = (krow & 7) << 4;
            bf16x8 ka0 = *(const bf16x8*)(kbase + ((g * 16) ^ sw));
            bf16x8 ka1 = *(const bf16x8*)(kbase + ((g * 16 + 64) ^ sw));
            f32x4 s = {0.f, 0.f, 0.f, 0.f};
            s = MFMA16(ka0, qf0, s);
            s = MFMA16(ka1, qf1, s);

            f32x4 ev;
            #pragma unroll
            for (int r = 0; r < 4; ++r) {
                int d = i_row - (c0 + nt * 16 + g * 4 + r);
                ev[r] = (d >= 0 && ((bmask[d >> 6] >> (d & 63)) & 1ull))
                          ? __expf(s[r]) * rsinv : 0.f;
            }
            // attn: row i_row, cols c0 + nt*16 + 4g .. +3 (vector NT store)
            __builtin_nontemporal_store(ev,
                (f32x4*)(arow + c0 + nt * 16 + g * 4));
            // P (normalized, bf16): row = q-local (lane&15), col = k-local
            unsigned long long pk =
                  (unsigned long long)f2bf(ev[0])
                | ((unsigned long long)f2bf(ev[1]) << 16)
                | ((unsigned long long)f2bf(ev[2]) << 32)
                | ((unsigned long long)f2bf(ev[3]) << 48);
            *(unsigned long long*)(prow + ((nt * 32 + g * 8) ^ swp)) = pk;
        }

        // PV: A = P (q x k), B = V (k x d) — both layouts unchanged
        const char* pbase = (const char*)&P_lds[wave][0] + (lane & 15) * 128;
        bf16x8 pa0 = *(const bf16x8*)(pbase + ((g * 16) ^ swp));
        bf16x8 pa1 = *(const bf16x8*)(pbase + ((g * 16 + 64) ^ swp));
        #pragma unroll
        for (int dt = 0; dt < 4; ++dt) {
            int vrow = dt * 16 + (lane & 15);
            const char* vbase = (const char*)V_lds + vrow * 128;
            int sw = (vrow & 7) << 4;
            bf16x8 vb0 = *(const bf16x8*)(vbase + ((g * 16) ^ sw));
            bf16x8 vb1 = *(const bf16x8*)(vbase + ((g * 16 + 64) ^ sw));
            o[dt] = MFMA16(pa0, vb0, o[dt]);
            o[dt] = MFMA16(pa1, vb1, o[dt]);
        }
    }

    // ---------------- ctx store (bf16, already normalized) ----------------
    // PV output rows are q-local g*4+r, cols dt*16+(lane&15)
    #pragma unroll
    for (int dt = 0; dt < 4; ++dt) {
        int d = dt * 16 + (lane & 15);
        #pragma unroll
        for (int r = 0; r < 4; ++r) {
            int i = i0 + wave * 16 + g * 4 + r;
            ctxb[((size_t)(b * SEQ + i)) * DMODEL + h * DEPTH + d] = f2bf(o[dt][r]);
        }
    }
}

// ---------------------------------------------------------------------------
extern "C" void kernel_launch(void* const* d_in, const int* in_sizes, int n_in,
                              void* d_out, int out_size, void* d_ws, size_t ws_size,
                              hipStream_t stream) {
    const float* v  = (const float*)d_in[0];
    const float* k  = (const float*)d_in[1];
    const float* q  = (const float*)d_in[2];
    const float* Wq = (const float*)d_in[3];
    const float* bq = (const float*)d_in[4];
    const float* Wk = (const float*)d_in[5];
    const float* bk = (const float*)d_in[6];
    const float* Wv = (const float*)d_in[7];
    const float* bv = (const float*)d_in[8];
    const float* Wo = (const float*)d_in[9];
    const float* bo = (const float*)d_in[10];

    float* out  = (float*)d_out;                   // [B*S, D]
    float* attn = out + 4194304;                   // [B, H, S, S]  (512 MB)

    // --- d_ws layout (34 MB) — everything that must survive attn_mfma ---
    unsigned short* qbb  = (unsigned short*)d_ws;            // 8 MB bf16
    unsigned short* kbb  = qbb  + 4194304;                   // 8 MB
    unsigned short* vbT  = kbb  + 4194304;                   // 8 MB
    unsigned short* ctxb = vbT  + 4194304;                   // 8 MB
    unsigned short* WoT  = ctxb + 4194304;                   // 2 MB

    // --- scratch inside attn region (dead before attn_mfma writes it) ---
    unsigned short* qb16 = (unsigned short*)attn;            // 8 MB
    unsigned short* kb16 = qb16 + 4194304;                   // 8 MB
    unsigned short* vb16 = kb16 + 4194304;                   // 8 MB
    unsigned short* WqT  = vb16 + 4194304;                   // 2 MB
    unsigned short* WkT  = WqT  + 1048576;                   // 2 MB
    unsigned short* WvT  = WkT  + 1048576;                   // 2 MB

    cvt_inputs<<<dim3(2048, 3), 256, 0, stream>>>(q, k, v, qb16, kb16, vb16);
    cvt_w<<<dim3(16, 16, 4), 256, 0, stream>>>(Wq, Wk, Wv, Wo, WqT, WkT, WvT, WoT);

    // fused QKV projections, all K=1024 (768 blocks = 3/CU)
    gemm_qkv<<<dim3(8, 32, 3), 256, 0, stream>>>(
        qb16, kb16, vb16, WqT, WkT, WvT, bq, bk, bv, qbb, kbb, vbT);

    attn_mfma<<<dim3(SEQ / 64, NHEAD, BATCH), 256, 0, stream>>>(qbb, kbb, vbT, attn, ctxb);

    gemm_out<<<dim3(8, 32), 256, 0, stream>>>(ctxb, WoT, bo, out);
}